// Round 2
// baseline (12809.230 us; speedup 1.0000x reference)
//
#include <hip/hip_runtime.h>

// 2-layer masked LSTM encoder, B=64 T=512 E=256 U=512 V=32000.
// Strategy: per-step GEMM z = [x_t | h] @ [Wx;Wh] via bf16 MFMA, weights
// VGPR-resident per workgroup, persistent kernels with slot-array barrier.

typedef __attribute__((ext_vector_type(8))) short short8;
typedef __attribute__((ext_vector_type(4))) float f32x4;

#define Bsz 64
#define Tsz 512
#define Esz 256
#define Usz 512
#define Vsz 32000
#define G4  2048
#define NWG 128   // workgroups per recurrence kernel; each owns 4 u-values (16 z-cols)

__device__ __forceinline__ unsigned short f2bf(float f){
  unsigned u = __float_as_uint(f);
  u = (u + 0x7FFFu + ((u >> 16) & 1u)) >> 16;   // round-to-nearest-even
  return (unsigned short)u;
}
__device__ __forceinline__ float sigmoidf_(float x){
  return 1.0f / (1.0f + __expf(-x));
}
__device__ __forceinline__ float tanhf_(float x){
  float e = __expf(2.0f * x);
  return (e - 1.0f) / (e + 1.0f);
}

// ---------------- prologue kernels ----------------

__global__ void conv_bf16_kernel(const float* __restrict__ in,
                                 unsigned short* __restrict__ out, int n){
  int i = blockIdx.x * blockDim.x + threadIdx.x;
  int stride = gridDim.x * blockDim.x;
  for (; i < n; i += stride) out[i] = f2bf(in[i]);
}

// Pre-swizzle [Wx;Wh] into per-lane MFMA B-fragment order:
// out[((wg*KT + kt)*64 + lane)*8 + j] = W[k][col], k = kt*32 + (lane>>4)*8 + j,
// col = gate*512 + wg*4 + ul with (gate,ul) from lane&15 = gate*4+ul.
template<int KT, int KX>
__global__ void build_wst_kernel(const float* __restrict__ Wx,
                                 const float* __restrict__ Wh,
                                 unsigned short* __restrict__ out){
  int n = NWG * KT * 64 * 8;
  int i = blockIdx.x * blockDim.x + threadIdx.x;
  int stride = gridDim.x * blockDim.x;
  for (; i < n; i += stride){
    int j    = i & 7;
    int lane = (i >> 3) & 63;
    int kt   = (i >> 9) % KT;
    int wg   = (i >> 9) / KT;
    int k    = kt * 32 + (lane >> 4) * 8 + j;
    int c    = lane & 15;
    int col  = (c >> 2) * Usz + wg * 4 + (c & 3);
    float v  = (k < KX) ? Wx[(size_t)k * G4 + col]
                        : Wh[(size_t)(k - KX) * G4 + col];
    out[i] = f2bf(v);
  }
}

__global__ void init_state_kernel(unsigned short* hbuf0, unsigned short* hbuf1,
                                  int* slots0, int* slots1){
  int i = blockIdx.x * blockDim.x + threadIdx.x;
  int n = 2 * Bsz * Usz;
  if (i < n){ hbuf0[i] = 0; hbuf1[i] = 0; }
  if (i < NWG){ slots0[i] = 0; slots1[i] = 0; }
}

// ---------------- recurrence kernel ----------------
// LAYER 0: A = [emb_t (K=256) | h (512)]  KT=24 k-tiles, KTH=8
// LAYER 1: A = [hs0_t (512)  | h (512)]  KT=32 k-tiles, KTH=16
// Grid: NWG blocks x 256 threads (4 waves = 4 M-tiles of 16 batch rows).
template<int LAYER, int KT, int KTH>
__global__ __launch_bounds__(256, 1) void lstm_layer_kernel(
    const int* __restrict__ x,
    const unsigned short* __restrict__ Wst,
    const float* __restrict__ bias,
    const unsigned short* __restrict__ seqin,   // L0: W_emb bf16 [V][E]; L1: hs0 [T][B][U]
    unsigned short* __restrict__ hs_out,        // L0: hs0 [T][B][U]; L1: unused
    unsigned short* __restrict__ hbuf,          // ping-pong [2][B][U] bf16
    int* __restrict__ slots,                    // NWG barrier slots
    float* __restrict__ out_h,
    float* __restrict__ out_c)
{
  const int tid  = threadIdx.x;
  const int wg   = blockIdx.x;
  const int wave = tid >> 6;
  const int lane = tid & 63;
  const int l15  = lane & 15;
  const int lg   = lane >> 4;

  // B-fragments: VGPR-resident for the whole kernel (pre-swizzled in ws)
  short8 Bf[KT];
  {
    const short8* wp = reinterpret_cast<const short8*>(Wst) + ((size_t)wg * KT) * 64 + lane;
    #pragma unroll
    for (int kt = 0; kt < KT; ++kt) Bf[kt] = wp[kt * 64];
  }

  const int   u      = wg * 4 + (l15 & 3);          // owned hidden unit (owner lanes l15<4)
  const float bias_l = bias[(l15 >> 2) * Usz + u];  // per-fragment-column bias

  const int arow  = wave * 16 + l15;      // A-matrix row this lane loads (batch index)
  const int berow = wave * 16 + lg * 4;   // first C/D row this lane holds

  float cc[4] = {0.f,0.f,0.f,0.f};
  float hh[4] = {0.f,0.f,0.f,0.f};

  for (int t = 0; t < Tsz; ++t){
    const unsigned short* hin  = hbuf + (size_t)(t & 1) * (Bsz * Usz);
    unsigned short*       hout = hbuf + (size_t)((t + 1) & 1) * (Bsz * Usz);

    // ---- A fragments: [x-part | h-part]
    short8 Af[KT];
    if (LAYER == 0){
      const int tok = x[arow * Tsz + t];
      const unsigned short* er = seqin + (size_t)tok * Esz + lg * 8;
      #pragma unroll
      for (int kt = 0; kt < KTH; ++kt)
        Af[kt] = *reinterpret_cast<const short8*>(er + kt * 32);
    } else {
      const unsigned short* er = seqin + ((size_t)t * Bsz + arow) * Usz + lg * 8;
      #pragma unroll
      for (int kt = 0; kt < KTH; ++kt)
        Af[kt] = *reinterpret_cast<const short8*>(er + kt * 32);
    }
    {
      const unsigned short* hr = hin + (size_t)arow * Usz + lg * 8;
      #pragma unroll
      for (int kt = KTH; kt < KT; ++kt)
        Af[kt] = *reinterpret_cast<const short8*>(hr + (kt - KTH) * 32);
    }

    // ---- MFMA chain, two accumulators to break dependency
    f32x4 acc0 = {0.f,0.f,0.f,0.f};
    f32x4 acc1 = {0.f,0.f,0.f,0.f};
    #pragma unroll
    for (int kt = 0; kt < KT; kt += 2){
      acc0 = __builtin_amdgcn_mfma_f32_16x16x32_bf16(Af[kt],   Bf[kt],   acc0, 0, 0, 0);
      acc1 = __builtin_amdgcn_mfma_f32_16x16x32_bf16(Af[kt+1], Bf[kt+1], acc1, 0, 0, 0);
    }

    // ---- epilogue: lane l15=c holds z[b][col], col order [i(4u) f(4u) g(4u) o(4u)]
    #pragma unroll
    for (int r = 0; r < 4; ++r){
      float z  = acc0[r] + acc1[r] + bias_l;   // each lane adds ITS column's bias pre-shfl
      float zf = __shfl_xor(z, 4);
      float zg = __shfl_xor(z, 8);
      float zo = __shfl_xor(z, 12);
      if (l15 < 4){                            // owner lanes: i-column holders
        const int b = berow + r;
        float iv = sigmoidf_(z);
        float fv = sigmoidf_(zf);
        float gv = tanhf_(zg);
        float ov = sigmoidf_(zo);
        float cn = fv * cc[r] + iv * gv;
        float hn = ov * tanhf_(cn);
        if (x[b * Tsz + t] != 0){ cc[r] = cn; hh[r] = hn; }   // mask semantics
        unsigned short hb = f2bf(hh[r]);
        hout[(size_t)b * Usz + u] = hb;
        if (LAYER == 0) hs_out[((size_t)t * Bsz + b) * Usz + u] = hb;
      }
    }

    // ---- grid barrier: slot writes + all-poll-all (no atomics RMW)
    if (t != Tsz - 1){
      __syncthreads();                         // drains this WG's stores (vmcnt 0)
      if (tid == 0){
        __threadfence();                       // agent-scope visibility of h stores
        __hip_atomic_store(&slots[wg], t + 1, __ATOMIC_RELAXED, __HIP_MEMORY_SCOPE_AGENT);
      }
      if (wave == 0){
        for (;;){
          int s0 = __hip_atomic_load(&slots[lane],      __ATOMIC_RELAXED, __HIP_MEMORY_SCOPE_AGENT);
          int s1 = __hip_atomic_load(&slots[lane + 64], __ATOMIC_RELAXED, __HIP_MEMORY_SCOPE_AGENT);
          if (__all(s0 > t && s1 > t)) break;
          __builtin_amdgcn_s_sleep(1);
        }
        __threadfence();                       // acquire side: invalidate L1 before next h reads
      }
      __syncthreads();
    }
  }

  // final h,c -> output (fp32, unrounded running values)
  if (l15 < 4){
    #pragma unroll
    for (int r = 0; r < 4; ++r){
      const int b = berow + r;
      out_h[(size_t)b * Usz + u] = hh[r];
      out_c[(size_t)b * Usz + u] = cc[r];
    }
  }
}

// ---------------- launch ----------------

extern "C" void kernel_launch(void* const* d_in, const int* in_sizes, int n_in,
                              void* d_out, int out_size, void* d_ws, size_t ws_size,
                              hipStream_t stream)
{
  const int*   x     = (const int*)  d_in[0];
  const float* W_emb = (const float*)d_in[1];
  const float* Wx0   = (const float*)d_in[2];
  const float* Wh0   = (const float*)d_in[3];
  const float* b0    = (const float*)d_in[4];
  const float* Wx1   = (const float*)d_in[5];
  const float* Wh1   = (const float*)d_in[6];
  const float* b1    = (const float*)d_in[7];
  float* out = (float*)d_out;

  char* ws = (char*)d_ws;
  size_t off = 0;
  auto alloc = [&](size_t bytes) -> char* {
    char* p = ws + off;
    off = (off + bytes + 255) & ~(size_t)255;
    return p;
  };
  unsigned short* embbf = (unsigned short*)alloc((size_t)Vsz * Esz * 2);        // 16.4 MB
  unsigned short* wst0  = (unsigned short*)alloc((size_t)NWG * 24 * 64 * 8 * 2);// 3.1 MB
  unsigned short* wst1  = (unsigned short*)alloc((size_t)NWG * 32 * 64 * 8 * 2);// 4.2 MB
  unsigned short* hs0   = (unsigned short*)alloc((size_t)Tsz * Bsz * Usz * 2);  // 33.6 MB
  unsigned short* hbuf0 = (unsigned short*)alloc((size_t)2 * Bsz * Usz * 2);
  unsigned short* hbuf1 = (unsigned short*)alloc((size_t)2 * Bsz * Usz * 2);
  int* slots0 = (int*)alloc(NWG * sizeof(int));
  int* slots1 = (int*)alloc(NWG * sizeof(int));
  if (off > ws_size) return;   // workspace too small -> loud validation failure

  // prologue: weight conversion/swizzle + state init (re-done every call; ws is poisoned)
  conv_bf16_kernel<<<2048, 256, 0, stream>>>(W_emb, embbf, Vsz * Esz);
  build_wst_kernel<24, 256><<<1024, 256, 0, stream>>>(Wx0, Wh0, wst0);
  build_wst_kernel<32, 512><<<1024, 256, 0, stream>>>(Wx1, Wh1, wst1);
  init_state_kernel<<<(2 * Bsz * Usz + 255) / 256, 256, 0, stream>>>(hbuf0, hbuf1, slots0, slots1);

  // layer 0: A = [emb | h], K = 768
  lstm_layer_kernel<0, 24, 8><<<NWG, 256, 0, stream>>>(
      x, wst0, b0, embbf, hs0, hbuf0, slots0, out, out + Bsz * Usz);
  // layer 1: A = [hs0_t | h], K = 1024
  lstm_layer_kernel<1, 32, 16><<<NWG, 256, 0, stream>>>(
      x, wst1, b1, hs0, nullptr, hbuf1, slots1, out + 2 * Bsz * Usz, out + 3 * Bsz * Usz);
}

// Round 5
// 9475.298 us; speedup vs baseline: 1.3519x; 1.3519x over previous
//
#include <hip/hip_runtime.h>

// 2-layer masked LSTM encoder, B=64 T=512 E=256 U=512 V=32000.
// Persistent-grid recurrence; per-step GEMM z=[x_t|h]@[Wx;Wh] via bf16 MFMA,
// weights VGPR-resident. R2 change: targeted cross-XCD coherence (agent-scope
// stores + sc0/sc1 vector loads for h, no __threadfence/wbl2), lean spin barrier.

typedef __attribute__((ext_vector_type(8))) short short8;
typedef __attribute__((ext_vector_type(4))) float f32x4;

#define Bsz 64
#define Tsz 512
#define Esz 256
#define Usz 512
#define Vsz 32000
#define G4  2048
#define NWG 128   // workgroups per recurrence kernel; each owns 4 u-values (16 z-cols)

__device__ __forceinline__ unsigned short f2bf(float f){
  unsigned u = __float_as_uint(f);
  u = (u + 0x7FFFu + ((u >> 16) & 1u)) >> 16;   // round-to-nearest-even
  return (unsigned short)u;
}
__device__ __forceinline__ float sigmoidf_(float x){
  return 1.0f / (1.0f + __expf(-x));
}
__device__ __forceinline__ float tanhf_(float x){
  float e = __expf(2.0f * x);
  return (e - 1.0f) / (e + 1.0f);
}

// ---------------- prologue kernels ----------------

__global__ void conv_bf16_kernel(const float* __restrict__ in,
                                 unsigned short* __restrict__ out, int n){
  int i = blockIdx.x * blockDim.x + threadIdx.x;
  int stride = gridDim.x * blockDim.x;
  for (; i < n; i += stride) out[i] = f2bf(in[i]);
}

// Pre-swizzle [Wx;Wh] into per-lane MFMA B-fragment order:
// out[((wg*KT + kt)*64 + lane)*8 + j] = W[k][col], k = kt*32 + (lane>>4)*8 + j,
// col = gate*512 + wg*4 + ul with (gate,ul) from lane&15 = gate*4+ul.
template<int KT, int KX>
__global__ void build_wst_kernel(const float* __restrict__ Wx,
                                 const float* __restrict__ Wh,
                                 unsigned short* __restrict__ out){
  int n = NWG * KT * 64 * 8;
  int i = blockIdx.x * blockDim.x + threadIdx.x;
  int stride = gridDim.x * blockDim.x;
  for (; i < n; i += stride){
    int j    = i & 7;
    int lane = (i >> 3) & 63;
    int kt   = (i >> 9) % KT;
    int wg   = (i >> 9) / KT;
    int k    = kt * 32 + (lane >> 4) * 8 + j;
    int c    = lane & 15;
    int col  = (c >> 2) * Usz + wg * 4 + (c & 3);
    float v  = (k < KX) ? Wx[(size_t)k * G4 + col]
                        : Wh[(size_t)(k - KX) * G4 + col];
    out[i] = f2bf(v);
  }
}

__global__ void init_state_kernel(unsigned int* hbuf0, unsigned int* hbuf1,
                                  int* slots0, int* slots1){
  int i = blockIdx.x * blockDim.x + threadIdx.x;
  int n = 2 * Bsz * (Usz / 2);              // 2 ping-pong buffers of [B][U/2] uints
  if (i < n){ hbuf0[i] = 0u; hbuf1[i] = 0u; }
  if (i < NWG){ slots0[i] = 0; slots1[i] = 0; }
}

// ---------------- recurrence kernel ----------------
// LAYER 0: A = [emb_t (K=256) | h (512)]  KTH=8 x-frags + 16 h-frags
// LAYER 1: A = [hs0_t (512)  | h (512)]  KTH=16 x-frags + 16 h-frags
// Grid: NWG blocks x 256 threads (4 waves = 4 M-tiles of 16 batch rows).
template<int LAYER, int KTH>
__global__ __launch_bounds__(256, 1) void lstm_layer_kernel(
    const int* __restrict__ x,
    const unsigned short* __restrict__ Wst,
    const float* __restrict__ bias,
    const unsigned short* __restrict__ seqin,   // L0: W_emb bf16 [V][E]; L1: hs0 [T][B][U]
    unsigned short* __restrict__ hs_out,        // L0: hs0 [T][B][U]; L1: unused
    unsigned int* __restrict__ hbuf,            // ping-pong [2][B][U/2] packed bf16 pairs
    int* __restrict__ slots,                    // NWG barrier slots
    float* __restrict__ out_h,
    float* __restrict__ out_c)
{
  constexpr int KT = KTH + 16;                  // total k-tiles (h-part is always 16)
  const int tid  = threadIdx.x;
  const int wg   = blockIdx.x;
  const int lane = tid & 63;
  const int wave = tid >> 6;
  const int l15  = lane & 15;
  const int lg   = lane >> 4;

  // B-fragments: VGPR-resident for the whole kernel (pre-swizzled in ws)
  short8 Bf[KT];
  {
    const short8* wp = reinterpret_cast<const short8*>(Wst) + ((size_t)wg * KT) * 64 + lane;
    #pragma unroll
    for (int kt = 0; kt < KT; ++kt) Bf[kt] = wp[kt * 64];
  }

  const int   u      = wg * 4 + (l15 & 3);          // owned hidden unit (owner lanes l15<4)
  const float bias_l = bias[(l15 >> 2) * Usz + u];  // per-fragment-column bias

  const int arow  = wave * 16 + l15;      // A-matrix row this lane loads (batch index)
  const int berow = wave * 16 + lg * 4;   // first C/D row this lane holds

  float cc[4] = {0.f,0.f,0.f,0.f};
  float hh[4] = {0.f,0.f,0.f,0.f};

  for (int t = 0; t < Tsz; ++t){
    // ---- x-part A fragments (plain, L2-cached; issue before h so latency hides)
    short8 Ax[KTH];
    if (LAYER == 0){
      const int tok = x[arow * Tsz + t];
      const unsigned short* er = seqin + (size_t)tok * Esz + lg * 8;
      #pragma unroll
      for (int kt = 0; kt < KTH; ++kt)
        Ax[kt] = *reinterpret_cast<const short8*>(er + kt * 32);
    } else {
      const unsigned short* er = seqin + ((size_t)t * Bsz + arow) * Usz + lg * 8;
      #pragma unroll
      for (int kt = 0; kt < KTH; ++kt)
        Ax[kt] = *reinterpret_cast<const short8*>(er + kt * 32);
    }

    // ---- h-part: 16 coherent (L2-bypassing) dwordx4 loads + single drain.
    // Fragment i covers h[arow][i*32 + lg*8 .. +7]; byte base = row + lg*16, stride 64.
    const char* hp = (const char*)hbuf + ((size_t)(t & 1) << 16) + (size_t)arow * 1024 + lg * 16;
    short8 H0,H1,H2,H3,H4,H5,H6,H7,H8,H9,H10,H11,H12,H13,H14,H15;
    asm volatile(
      "global_load_dwordx4 %0,  %16, off sc0 sc1\n\t"
      "global_load_dwordx4 %1,  %16, off offset:64  sc0 sc1\n\t"
      "global_load_dwordx4 %2,  %16, off offset:128 sc0 sc1\n\t"
      "global_load_dwordx4 %3,  %16, off offset:192 sc0 sc1\n\t"
      "global_load_dwordx4 %4,  %16, off offset:256 sc0 sc1\n\t"
      "global_load_dwordx4 %5,  %16, off offset:320 sc0 sc1\n\t"
      "global_load_dwordx4 %6,  %16, off offset:384 sc0 sc1\n\t"
      "global_load_dwordx4 %7,  %16, off offset:448 sc0 sc1\n\t"
      "global_load_dwordx4 %8,  %16, off offset:512 sc0 sc1\n\t"
      "global_load_dwordx4 %9,  %16, off offset:576 sc0 sc1\n\t"
      "global_load_dwordx4 %10, %16, off offset:640 sc0 sc1\n\t"
      "global_load_dwordx4 %11, %16, off offset:704 sc0 sc1\n\t"
      "global_load_dwordx4 %12, %16, off offset:768 sc0 sc1\n\t"
      "global_load_dwordx4 %13, %16, off offset:832 sc0 sc1\n\t"
      "global_load_dwordx4 %14, %16, off offset:896 sc0 sc1\n\t"
      "global_load_dwordx4 %15, %16, off offset:960 sc0 sc1\n\t"
      "s_waitcnt vmcnt(0)"
      : "=&v"(H0),"=&v"(H1),"=&v"(H2),"=&v"(H3),"=&v"(H4),"=&v"(H5),"=&v"(H6),"=&v"(H7),
        "=&v"(H8),"=&v"(H9),"=&v"(H10),"=&v"(H11),"=&v"(H12),"=&v"(H13),"=&v"(H14),"=&v"(H15)
      : "v"(hp)
      : "memory");
    __builtin_amdgcn_sched_barrier(0);          // keep MFMAs below the drain (rule #18)

    // ---- MFMA chain, two accumulators to break dependency
    f32x4 acc0 = {0.f,0.f,0.f,0.f};
    f32x4 acc1 = {0.f,0.f,0.f,0.f};
    #pragma unroll
    for (int kt = 0; kt < KTH; kt += 2){
      acc0 = __builtin_amdgcn_mfma_f32_16x16x32_bf16(Ax[kt],   Bf[kt],   acc0, 0, 0, 0);
      acc1 = __builtin_amdgcn_mfma_f32_16x16x32_bf16(Ax[kt+1], Bf[kt+1], acc1, 0, 0, 0);
    }
    {
      short8 Hf[16] = {H0,H1,H2,H3,H4,H5,H6,H7,H8,H9,H10,H11,H12,H13,H14,H15};
      #pragma unroll
      for (int i = 0; i < 16; i += 2){
        acc0 = __builtin_amdgcn_mfma_f32_16x16x32_bf16(Hf[i],   Bf[KTH+i],   acc0, 0, 0, 0);
        acc1 = __builtin_amdgcn_mfma_f32_16x16x32_bf16(Hf[i+1], Bf[KTH+i+1], acc1, 0, 0, 0);
      }
    }

    // ---- epilogue: lane l15=c holds z[b][col], col order [i(4u) f(4u) g(4u) o(4u)]
    unsigned int* hout = hbuf + (size_t)((t + 1) & 1) * (Bsz * Usz / 2);
    #pragma unroll
    for (int r = 0; r < 4; ++r){
      float z  = acc0[r] + acc1[r] + bias_l;   // each lane adds ITS column's bias pre-shfl
      float zf = __shfl_xor(z, 4);
      float zg = __shfl_xor(z, 8);
      float zo = __shfl_xor(z, 12);
      if (l15 < 4){                            // owner lanes: i-column holders
        const int b = berow + r;
        float iv = sigmoidf_(z);
        float fv = sigmoidf_(zf);
        float gv = tanhf_(zg);
        float ov = sigmoidf_(zo);
        float cn = fv * cc[r] + iv * gv;
        float hn = ov * tanhf_(cn);
        if (x[b * Tsz + t] != 0){ cc[r] = cn; hh[r] = hn; }   // mask semantics
        unsigned int hb = f2bf(hh[r]);
        unsigned int pb = (unsigned int)__shfl_xor((int)hb, 1);   // partner u's bf16
        if ((l15 & 1) == 0){
          // pack (u, u+1) -> one uint; agent-scope store is cross-XCD coherent, no fence
          __hip_atomic_store(hout + (size_t)b * (Usz/2) + wg * 2 + (l15 >> 1),
                             hb | (pb << 16), __ATOMIC_RELAXED, __HIP_MEMORY_SCOPE_AGENT);
        }
        if (LAYER == 0) hs_out[((size_t)t * Bsz + b) * Usz + u] = f2bf(hh[r]);
      }
    }

    // ---- grid barrier: syncthreads drains stores; slot store; all waves poll
    if (t != Tsz - 1){
      __syncthreads();                         // per-thread vmcnt(0) before s_barrier
      if (tid == 0)
        __hip_atomic_store(&slots[wg], t + 1, __ATOMIC_RELAXED, __HIP_MEMORY_SCOPE_AGENT);
      for (;;){
        int s0 = __hip_atomic_load(&slots[lane],      __ATOMIC_RELAXED, __HIP_MEMORY_SCOPE_AGENT);
        int s1 = __hip_atomic_load(&slots[lane + 64], __ATOMIC_RELAXED, __HIP_MEMORY_SCOPE_AGENT);
        if (__all((s0 > t) && (s1 > t))) break;
      }
    }
  }

  // final h,c -> output (fp32, unrounded running values)
  if (l15 < 4){
    #pragma unroll
    for (int r = 0; r < 4; ++r){
      const int b = berow + r;
      out_h[(size_t)b * Usz + u] = hh[r];
      out_c[(size_t)b * Usz + u] = cc[r];
    }
  }
}

// ---------------- launch ----------------

extern "C" void kernel_launch(void* const* d_in, const int* in_sizes, int n_in,
                              void* d_out, int out_size, void* d_ws, size_t ws_size,
                              hipStream_t stream)
{
  const int*   x     = (const int*)  d_in[0];
  const float* W_emb = (const float*)d_in[1];
  const float* Wx0   = (const float*)d_in[2];
  const float* Wh0   = (const float*)d_in[3];
  const float* b0    = (const float*)d_in[4];
  const float* Wx1   = (const float*)d_in[5];
  const float* Wh1   = (const float*)d_in[6];
  const float* b1    = (const float*)d_in[7];
  float* out = (float*)d_out;

  char* ws = (char*)d_ws;
  size_t off = 0;
  auto alloc = [&](size_t bytes) -> char* {
    char* p = ws + off;
    off = (off + bytes + 255) & ~(size_t)255;
    return p;
  };
  unsigned short* embbf = (unsigned short*)alloc((size_t)Vsz * Esz * 2);        // 16.4 MB
  unsigned short* wst0  = (unsigned short*)alloc((size_t)NWG * 24 * 64 * 8 * 2);// 3.1 MB
  unsigned short* wst1  = (unsigned short*)alloc((size_t)NWG * 32 * 64 * 8 * 2);// 4.2 MB
  unsigned short* hs0   = (unsigned short*)alloc((size_t)Tsz * Bsz * Usz * 2);  // 33.6 MB
  unsigned int*   hbuf0 = (unsigned int*)alloc((size_t)2 * Bsz * (Usz/2) * 4);  // 128 KB (64K-aligned by construction)
  unsigned int*   hbuf1 = (unsigned int*)alloc((size_t)2 * Bsz * (Usz/2) * 4);
  int* slots0 = (int*)alloc(NWG * sizeof(int));
  int* slots1 = (int*)alloc(NWG * sizeof(int));
  if (off > ws_size) return;   // workspace too small -> loud validation failure

  // prologue: weight conversion/swizzle + state init (re-done every call; ws is poisoned)
  conv_bf16_kernel<<<2048, 256, 0, stream>>>(W_emb, embbf, Vsz * Esz);
  build_wst_kernel<24, 256><<<1024, 256, 0, stream>>>(Wx0, Wh0, wst0);
  build_wst_kernel<32, 512><<<1024, 256, 0, stream>>>(Wx1, Wh1, wst1);
  init_state_kernel<<<(2 * Bsz * (Usz/2) + 255) / 256, 256, 0, stream>>>(hbuf0, hbuf1, slots0, slots1);

  // layer 0: A = [emb | h], K = 768
  lstm_layer_kernel<0, 8><<<NWG, 256, 0, stream>>>(
      x, wst0, b0, embbf, hs0, hbuf0, slots0, out, out + Bsz * Usz);
  // layer 1: A = [hs0_t | h], K = 1024
  lstm_layer_kernel<1, 16><<<NWG, 256, 0, stream>>>(
      x, wst1, b1, hs0, nullptr, hbuf1, slots1, out + 2 * Bsz * Usz, out + 3 * Bsz * Usz);
}

// Round 12
// 7290.175 us; speedup vs baseline: 1.7571x; 1.2997x over previous
//
#include <hip/hip_runtime.h>

// 2-layer masked LSTM encoder, B=64 T=512 E=256 U=512 V=32000.
// Persistent-grid recurrence; per-step GEMM z=[x_t|h]@[Wx;Wh] via bf16 MFMA,
// weights VGPR-resident; targeted cross-XCD coherence (agent stores + sc0/sc1
// loads). R6: hierarchical epoch barrier (WG0 sweeps slots, publishes one
// epoch flag; others poll it with ONE lane + s_sleep) to kill MALL poll
// contention. R11: bounded-spin watchdog so any barrier bug -> validation
// failure, never a container hang.

typedef __attribute__((ext_vector_type(8))) short short8;
typedef __attribute__((ext_vector_type(4))) float f32x4;

#define Bsz 64
#define Tsz 512
#define Esz 256
#define Usz 512
#define Vsz 32000
#define G4  2048
#define NWG 128        // workgroups per recurrence kernel; each owns 4 u-values (16 z-cols)
#define SPIN_MAX 100000  // watchdog: normal waits are ~1e2 iterations

__device__ __forceinline__ unsigned short f2bf(float f){
  unsigned u = __float_as_uint(f);
  u = (u + 0x7FFFu + ((u >> 16) & 1u)) >> 16;   // round-to-nearest-even
  return (unsigned short)u;
}
__device__ __forceinline__ float sigmoidf_(float x){
  return 1.0f / (1.0f + __expf(-x));
}
__device__ __forceinline__ float tanhf_(float x){
  float e = __expf(2.0f * x);
  return (e - 1.0f) / (e + 1.0f);
}

// ---------------- prologue kernels ----------------

__global__ void conv_bf16_kernel(const float* __restrict__ in,
                                 unsigned short* __restrict__ out, int n){
  int i = blockIdx.x * blockDim.x + threadIdx.x;
  int stride = gridDim.x * blockDim.x;
  for (; i < n; i += stride) out[i] = f2bf(in[i]);
}

// Pre-swizzle [Wx;Wh] into per-lane MFMA B-fragment order:
// out[((wg*KT + kt)*64 + lane)*8 + j] = W[k][col], k = kt*32 + (lane>>4)*8 + j,
// col = gate*512 + wg*4 + ul with (gate,ul) from lane&15 = gate*4+ul.
template<int KT, int KX>
__global__ void build_wst_kernel(const float* __restrict__ Wx,
                                 const float* __restrict__ Wh,
                                 unsigned short* __restrict__ out){
  int n = NWG * KT * 64 * 8;
  int i = blockIdx.x * blockDim.x + threadIdx.x;
  int stride = gridDim.x * blockDim.x;
  for (; i < n; i += stride){
    int j    = i & 7;
    int lane = (i >> 3) & 63;
    int kt   = (i >> 9) % KT;
    int wg   = (i >> 9) / KT;
    int k    = kt * 32 + (lane >> 4) * 8 + j;
    int c    = lane & 15;
    int col  = (c >> 2) * Usz + wg * 4 + (c & 3);
    float v  = (k < KX) ? Wx[(size_t)k * G4 + col]
                        : Wh[(size_t)(k - KX) * G4 + col];
    out[i] = f2bf(v);
  }
}

__global__ void init_state_kernel(unsigned int* hbuf0, unsigned int* hbuf1,
                                  int* slots0, int* slots1, int* epochs){
  int i = blockIdx.x * blockDim.x + threadIdx.x;
  int n = 2 * Bsz * (Usz / 2);              // 2 ping-pong buffers of [B][U/2] uints
  if (i < n){ hbuf0[i] = 0u; hbuf1[i] = 0u; }
  if (i < NWG){ slots0[i] = 0; slots1[i] = 0; }
  if (i < 2){ epochs[i] = 0; }
}

// ---------------- recurrence kernel ----------------
// LAYER 0: A = [emb_t (K=256) | h (512)]  KTH=8 x-frags + 16 h-frags
// LAYER 1: A = [hs0_t (512)  | h (512)]  KTH=16 x-frags + 16 h-frags
// Grid: NWG blocks x 256 threads (4 waves = 4 M-tiles of 16 batch rows).
template<int LAYER, int KTH>
__global__ __launch_bounds__(256, 1) void lstm_layer_kernel(
    const int* __restrict__ x,
    const unsigned short* __restrict__ Wst,
    const float* __restrict__ bias,
    const unsigned short* __restrict__ seqin,   // L0: W_emb bf16 [V][E]; L1: hs0 [T][B][U]
    unsigned short* __restrict__ hs_out,        // L0: hs0 [T][B][U]; L1: unused
    unsigned int* __restrict__ hbuf,            // ping-pong [2][B][U/2] packed bf16 pairs
    int* __restrict__ slots,                    // NWG barrier slots
    int* __restrict__ epoch,                    // single aggregated epoch flag
    float* __restrict__ out_h,
    float* __restrict__ out_c)
{
  constexpr int KT = KTH + 16;                  // total k-tiles (h-part is always 16)
  const int tid  = threadIdx.x;
  const int wg   = blockIdx.x;
  const int lane = tid & 63;
  const int wave = tid >> 6;
  const int l15  = lane & 15;
  const int lg   = lane >> 4;

  // B-fragments: VGPR-resident for the whole kernel (pre-swizzled in ws)
  short8 Bf[KT];
  {
    const short8* wp = reinterpret_cast<const short8*>(Wst) + ((size_t)wg * KT) * 64 + lane;
    #pragma unroll
    for (int kt = 0; kt < KT; ++kt) Bf[kt] = wp[kt * 64];
  }

  const int   u      = wg * 4 + (l15 & 3);          // owned hidden unit (owner lanes l15<4)
  const float bias_l = bias[(l15 >> 2) * Usz + u];  // per-fragment-column bias

  const int arow  = wave * 16 + l15;      // A-matrix row this lane loads (batch index)
  const int berow = wave * 16 + lg * 4;   // first C/D row this lane holds

  float cc[4] = {0.f,0.f,0.f,0.f};
  float hh[4] = {0.f,0.f,0.f,0.f};

  for (int t = 0; t < Tsz; ++t){
    // ---- x-part A fragments (plain, L2-cached; issue before h so latency hides)
    short8 Ax[KTH];
    if (LAYER == 0){
      const int tok = x[arow * Tsz + t];
      const unsigned short* er = seqin + (size_t)tok * Esz + lg * 8;
      #pragma unroll
      for (int kt = 0; kt < KTH; ++kt)
        Ax[kt] = *reinterpret_cast<const short8*>(er + kt * 32);
    } else {
      const unsigned short* er = seqin + ((size_t)t * Bsz + arow) * Usz + lg * 8;
      #pragma unroll
      for (int kt = 0; kt < KTH; ++kt)
        Ax[kt] = *reinterpret_cast<const short8*>(er + kt * 32);
    }

    // ---- h-part: 16 coherent (L2-bypassing) dwordx4 loads + single drain.
    // Fragment i covers h[arow][i*32 + lg*8 .. +7]; byte base = row + lg*16, stride 64.
    const char* hp = (const char*)hbuf + ((size_t)(t & 1) << 16) + (size_t)arow * 1024 + lg * 16;
    short8 H0,H1,H2,H3,H4,H5,H6,H7,H8,H9,H10,H11,H12,H13,H14,H15;
    asm volatile(
      "global_load_dwordx4 %0,  %16, off sc0 sc1\n\t"
      "global_load_dwordx4 %1,  %16, off offset:64  sc0 sc1\n\t"
      "global_load_dwordx4 %2,  %16, off offset:128 sc0 sc1\n\t"
      "global_load_dwordx4 %3,  %16, off offset:192 sc0 sc1\n\t"
      "global_load_dwordx4 %4,  %16, off offset:256 sc0 sc1\n\t"
      "global_load_dwordx4 %5,  %16, off offset:320 sc0 sc1\n\t"
      "global_load_dwordx4 %6,  %16, off offset:384 sc0 sc1\n\t"
      "global_load_dwordx4 %7,  %16, off offset:448 sc0 sc1\n\t"
      "global_load_dwordx4 %8,  %16, off offset:512 sc0 sc1\n\t"
      "global_load_dwordx4 %9,  %16, off offset:576 sc0 sc1\n\t"
      "global_load_dwordx4 %10, %16, off offset:640 sc0 sc1\n\t"
      "global_load_dwordx4 %11, %16, off offset:704 sc0 sc1\n\t"
      "global_load_dwordx4 %12, %16, off offset:768 sc0 sc1\n\t"
      "global_load_dwordx4 %13, %16, off offset:832 sc0 sc1\n\t"
      "global_load_dwordx4 %14, %16, off offset:896 sc0 sc1\n\t"
      "global_load_dwordx4 %15, %16, off offset:960 sc0 sc1\n\t"
      "s_waitcnt vmcnt(0)"
      : "=&v"(H0),"=&v"(H1),"=&v"(H2),"=&v"(H3),"=&v"(H4),"=&v"(H5),"=&v"(H6),"=&v"(H7),
        "=&v"(H8),"=&v"(H9),"=&v"(H10),"=&v"(H11),"=&v"(H12),"=&v"(H13),"=&v"(H14),"=&v"(H15)
      : "v"(hp)
      : "memory");
    __builtin_amdgcn_sched_barrier(0);          // keep MFMAs below the drain (rule #18)

    // ---- MFMA chain, two accumulators to break dependency
    f32x4 acc0 = {0.f,0.f,0.f,0.f};
    f32x4 acc1 = {0.f,0.f,0.f,0.f};
    #pragma unroll
    for (int kt = 0; kt < KTH; kt += 2){
      acc0 = __builtin_amdgcn_mfma_f32_16x16x32_bf16(Ax[kt],   Bf[kt],   acc0, 0, 0, 0);
      acc1 = __builtin_amdgcn_mfma_f32_16x16x32_bf16(Ax[kt+1], Bf[kt+1], acc1, 0, 0, 0);
    }
    {
      short8 Hf[16] = {H0,H1,H2,H3,H4,H5,H6,H7,H8,H9,H10,H11,H12,H13,H14,H15};
      #pragma unroll
      for (int i = 0; i < 16; i += 2){
        acc0 = __builtin_amdgcn_mfma_f32_16x16x32_bf16(Hf[i],   Bf[KTH+i],   acc0, 0, 0, 0);
        acc1 = __builtin_amdgcn_mfma_f32_16x16x32_bf16(Hf[i+1], Bf[KTH+i+1], acc1, 0, 0, 0);
      }
    }

    // ---- epilogue: lane l15=c holds z[b][col], col order [i(4u) f(4u) g(4u) o(4u)]
    unsigned int* hout = hbuf + (size_t)((t + 1) & 1) * (Bsz * Usz / 2);
    #pragma unroll
    for (int r = 0; r < 4; ++r){
      float z  = acc0[r] + acc1[r] + bias_l;   // each lane adds ITS column's bias pre-shfl
      float zf = __shfl_xor(z, 4);
      float zg = __shfl_xor(z, 8);
      float zo = __shfl_xor(z, 12);
      if (l15 < 4){                            // owner lanes: i-column holders
        const int b = berow + r;
        float iv = sigmoidf_(z);
        float fv = sigmoidf_(zf);
        float gv = tanhf_(zg);
        float ov = sigmoidf_(zo);
        float cn = fv * cc[r] + iv * gv;
        float hn = ov * tanhf_(cn);
        if (x[b * Tsz + t] != 0){ cc[r] = cn; hh[r] = hn; }   // mask semantics
        unsigned int hb = f2bf(hh[r]);
        unsigned int pb = (unsigned int)__shfl_xor((int)hb, 1);   // partner u's bf16
        if ((l15 & 1) == 0){
          // pack (u, u+1) -> one uint; agent-scope store is cross-XCD coherent, no fence
          __hip_atomic_store(hout + (size_t)b * (Usz/2) + wg * 2 + (l15 >> 1),
                             hb | (pb << 16), __ATOMIC_RELAXED, __HIP_MEMORY_SCOPE_AGENT);
        }
        if (LAYER == 0) hs_out[((size_t)t * Bsz + b) * Usz + u] = f2bf(hh[r]);
      }
    }

    // ---- hierarchical grid barrier (bounded-spin watchdog on all polls):
    //   all WGs: slot store (after syncthreads drains h-stores)
    //   WG0-wave0: sweep all slots, publish epoch
    //   other WGs: ONE lane polls epoch (low MALL traffic), syncthreads releases
    if (t != Tsz - 1){
      __syncthreads();                         // per-thread vmcnt(0) before s_barrier
      if (tid == 0)
        __hip_atomic_store(&slots[wg], t + 1, __ATOMIC_RELAXED, __HIP_MEMORY_SCOPE_AGENT);
      if (wg == 0){
        if (wave == 0){
          int guard = 0;
          for (;;){
            int s0 = __hip_atomic_load(&slots[lane],      __ATOMIC_RELAXED, __HIP_MEMORY_SCOPE_AGENT);
            int s1 = __hip_atomic_load(&slots[lane + 64], __ATOMIC_RELAXED, __HIP_MEMORY_SCOPE_AGENT);
            if (__all((s0 > t) && (s1 > t))) break;
            if (++guard > SPIN_MAX) break;     // watchdog: deadlock -> wrong result, not hang
            __builtin_amdgcn_s_sleep(1);
          }
          if (lane == 0)
            __hip_atomic_store(epoch, t + 1, __ATOMIC_RELAXED, __HIP_MEMORY_SCOPE_AGENT);
        }
      } else {
        if (tid == 0){
          int guard = 0;
          while (__hip_atomic_load(epoch, __ATOMIC_RELAXED, __HIP_MEMORY_SCOPE_AGENT) <= t){
            if (++guard > SPIN_MAX) break;     // watchdog
            __builtin_amdgcn_s_sleep(1);
          }
        }
      }
      __syncthreads();
    }
  }

  // final h,c -> output (fp32, unrounded running values)
  if (l15 < 4){
    #pragma unroll
    for (int r = 0; r < 4; ++r){
      const int b = berow + r;
      out_h[(size_t)b * Usz + u] = hh[r];
      out_c[(size_t)b * Usz + u] = cc[r];
    }
  }
}

// ---------------- launch ----------------

extern "C" void kernel_launch(void* const* d_in, const int* in_sizes, int n_in,
                              void* d_out, int out_size, void* d_ws, size_t ws_size,
                              hipStream_t stream)
{
  const int*   x     = (const int*)  d_in[0];
  const float* W_emb = (const float*)d_in[1];
  const float* Wx0   = (const float*)d_in[2];
  const float* Wh0   = (const float*)d_in[3];
  const float* b0    = (const float*)d_in[4];
  const float* Wx1   = (const float*)d_in[5];
  const float* Wh1   = (const float*)d_in[6];
  const float* b1    = (const float*)d_in[7];
  float* out = (float*)d_out;

  char* ws = (char*)d_ws;
  size_t off = 0;
  auto alloc = [&](size_t bytes) -> char* {
    char* p = ws + off;
    off = (off + bytes + 255) & ~(size_t)255;
    return p;
  };
  unsigned short* embbf = (unsigned short*)alloc((size_t)Vsz * Esz * 2);        // 16.4 MB
  unsigned short* wst0  = (unsigned short*)alloc((size_t)NWG * 24 * 64 * 8 * 2);// 3.1 MB
  unsigned short* wst1  = (unsigned short*)alloc((size_t)NWG * 32 * 64 * 8 * 2);// 4.2 MB
  unsigned short* hs0   = (unsigned short*)alloc((size_t)Tsz * Bsz * Usz * 2);  // 33.6 MB
  unsigned int*   hbuf0 = (unsigned int*)alloc((size_t)2 * Bsz * (Usz/2) * 4);  // 128 KB (64K-aligned by construction)
  unsigned int*   hbuf1 = (unsigned int*)alloc((size_t)2 * Bsz * (Usz/2) * 4);
  int* slots0 = (int*)alloc(NWG * sizeof(int));
  int* slots1 = (int*)alloc(NWG * sizeof(int));
  int* epochs = (int*)alloc(2 * sizeof(int));
  if (off > ws_size) return;   // workspace too small -> loud validation failure

  // prologue: weight conversion/swizzle + state init (re-done every call; ws is poisoned)
  conv_bf16_kernel<<<2048, 256, 0, stream>>>(W_emb, embbf, Vsz * Esz);
  build_wst_kernel<24, 256><<<1024, 256, 0, stream>>>(Wx0, Wh0, wst0);
  build_wst_kernel<32, 512><<<1024, 256, 0, stream>>>(Wx1, Wh1, wst1);
  init_state_kernel<<<(2 * Bsz * (Usz/2) + 255) / 256, 256, 0, stream>>>(hbuf0, hbuf1, slots0, slots1, epochs);

  // layer 0: A = [emb | h], K = 768
  lstm_layer_kernel<0, 8><<<NWG, 256, 0, stream>>>(
      x, wst0, b0, embbf, hs0, hbuf0, slots0, &epochs[0], out, out + Bsz * Usz);
  // layer 1: A = [hs0_t | h], K = 1024
  lstm_layer_kernel<1, 16><<<NWG, 256, 0, stream>>>(
      x, wst1, b1, hs0, nullptr, hbuf1, slots1, &epochs[1], out + 2 * Bsz * Usz, out + 3 * Bsz * Usz);
}